// Round 9
// baseline (305.512 us; speedup 1.0000x reference)
//
#include <hip/hip_runtime.h>
#include <math.h>

#define N_CLASSES 18
#define NMS_PRE   1000
#define K_NMS     500
#define POOL      4000      // 4 * NMS_PRE
#define LIST_CAP  2048
#define NREP      16        // replicated pass-0 histograms (atomic spread)
#define NSUB      16        // distributed compaction counters per level
#define SUBCAP    (LIST_CAP/NSUB)
#define IOU_THR   0.5f
#define SCORE_THR 0.01f

typedef unsigned long long ull;

struct Ptrs {
  const float* cent[4];
  const float* bbox[4];
  const float* cls[4];
  const float* pts[4];
  int off[4];
  int ntot;
};

__device__ __forceinline__ unsigned int fsort(float f){
  unsigned int b = __float_as_uint(f);
  return (b & 0x80000000u) ? ~b : (b | 0x80000000u);
}
__device__ __forceinline__ float fsort_inv(unsigned int k){
  unsigned int b = (k & 0x80000000u) ? (k & 0x7FFFFFFFu) : ~k;
  return __uint_as_float(b);
}
__device__ __forceinline__ float sigmoidf_(float x){
  return 1.0f / (1.0f + expf(-x));
}
__device__ __forceinline__ int level_of(int f, const Ptrs& P){
  return (f >= P.off[3]) ? 3 : (f >= P.off[2]) ? 2 : (f >= P.off[1]) ? 1 : 0;
}

// compare-exchange helpers for hybrid bitonic (desc).
__device__ __forceinline__ ull cx_keep(ull mine, ull part, bool keep_hi){
  ull mx = mine > part ? mine : part;
  ull mn = mine > part ? part : mine;
  return keep_hi ? mx : mn;
}
__device__ __forceinline__ void cxpair(ull &a, ull &b, bool a_hi){
  ull mx = a > b ? a : b;
  ull mn = a > b ? b : a;
  a = a_hi ? mx : mn;
  b = a_hi ? mn : mx;
}

// ---------------- stage 0: zero pass-0 histograms only ----------------------
__global__ void __launch_bounds__(256) init_kernel(unsigned int* hist_rep){
  int tid = blockIdx.x*256 + threadIdx.x;
  int stride = gridDim.x*256;
  for (int j = tid; j < NREP*4*2048; j += stride) hist_rep[j] = 0u;
}

// ---------------- stage 1: fused max-score key + pass-0 histogram -----------
// One thread per POINT-PAIR: 2 rows = 144B = 9x float4, all 16B-aligned.
__global__ void __launch_bounds__(512) compute_keys(Ptrs P, unsigned int* keys,
                        unsigned int* hist_rep){
  __shared__ unsigned int lh[2048];
  int t = threadIdx.x;
  for (int j = t; j < 2048; j += 512) lh[j] = 0u;
  int ip = blockIdx.x*512 + t;          // pair index
  int f  = ip << 1;
  int rep = blockIdx.x & (NREP - 1);
  bool valid = f < P.ntot;              // ntot even -> full pair
  int f0 = blockIdx.x << 10;            // first point of block
  int fL = min(f0 + 1023, P.ntot - 1);
  bool uni = (level_of(f0, P) == level_of(fL, P)) && (f0 + 1023 < P.ntot);
  int Lb = level_of(f0, P);

  float mA = 0.f, mB = 0.f, cA = 0.f, cB = 0.f;
  int L = 0;
  if (valid){
    L = level_of(f, P);
    int i = f - P.off[L];
    const float4* q = (const float4*)(P.cls[L] + (size_t)i * N_CLASSES);
    float4 q0 = q[0], q1 = q[1], q2 = q[2], q3 = q[3], q4 = q[4];
    float4 q5 = q[5], q6 = q[6], q7 = q[7], q8 = q[8];
    mA = fmaxf(fmaxf(fmaxf(q0.x,q0.y), fmaxf(q0.z,q0.w)),
         fmaxf(fmaxf(fmaxf(q1.x,q1.y), fmaxf(q1.z,q1.w)),
         fmaxf(fmaxf(fmaxf(q2.x,q2.y), fmaxf(q2.z,q2.w)),
         fmaxf(fmaxf(fmaxf(q3.x,q3.y), fmaxf(q3.z,q3.w)),
               fmaxf(q4.x,q4.y)))));
    mB = fmaxf(fmaxf(q4.z,q4.w),
         fmaxf(fmaxf(fmaxf(q5.x,q5.y), fmaxf(q5.z,q5.w)),
         fmaxf(fmaxf(fmaxf(q6.x,q6.y), fmaxf(q6.z,q6.w)),
         fmaxf(fmaxf(fmaxf(q7.x,q7.y), fmaxf(q7.z,q7.w)),
               fmaxf(fmaxf(q8.x,q8.y), fmaxf(q8.z,q8.w))))));
    const float2 c2 = *(const float2*)(P.cent[L] + i);   // i even -> 8B aligned
    cA = c2.x; cB = c2.y;
  }
  __syncthreads();      // lh zero-init visible

  if (valid){
    // sigmoid monotone => sig(max)*sig(cent) == max_c(sig(c)*sig(cent))
    float sA = sigmoidf_(mA) * sigmoidf_(cA);
    float sB = sigmoidf_(mB) * sigmoidf_(cB);
    unsigned int kA = fsort(sA), kB = fsort(sB);
    *(uint2*)(keys + f) = make_uint2(kA, kB);            // coalesced 8B/lane
    if (uni){
      atomicAdd(&lh[kA >> 21], 1u);
      atomicAdd(&lh[kB >> 21], 1u);
    } else {
      unsigned int* hb = hist_rep + ((rep*4) + L)*2048;
      atomicAdd(&hb[kA >> 21], 1u);
      atomicAdd(&hb[kB >> 21], 1u);
    }
  }
  __syncthreads();
  if (uni){
    unsigned int* hb = hist_rep + ((rep*4) + Lb)*2048;
    for (int j = t; j < 2048; j += 512){
      unsigned int v = lh[j];
      if (v) atomicAdd(&hb[j], v);
    }
  }
}

// ---------------- stage 2: second 11-bit histogram pass (pair/thread) -------
__global__ void __launch_bounds__(512) hist_level(Ptrs P, const unsigned int* keys,
                        const unsigned int* state, unsigned int* hist2){
  int ip = blockIdx.x*512 + threadIdx.x;
  int f = ip << 1;
  if (f < P.ntot){
    int L = level_of(f, P);              // pair never straddles a level
    uint2 kk = *(const uint2*)(keys + f);
    unsigned int Pfx = state[2*L];
    unsigned int hi = Pfx >> 21;
    if ((kk.x >> 21) == hi) atomicAdd(&hist2[L*2048 + ((kk.x >> 10) & 0x7FFu)], 1u);
    if ((kk.y >> 21) == hi) atomicAdd(&hist2[L*2048 + ((kk.y >> 10) & 0x7FFu)], 1u);
  }
}

// ---------------- scan + select: one block per level ------------------------
// Piggy-backed zeroing: pass 0 zeroes hist2; pass 1 zeroes lists+scnt.
__global__ void __launch_bounds__(256) scan_sel(const unsigned int* src, int nrep,
                        unsigned int* state, int pass,
                        unsigned int* hist2z, ull* listsz, unsigned int* scntz){
  __shared__ unsigned int lhist[2048];
  int L = blockIdx.x, t = threadIdx.x;
  if (pass == 0){
    for (int j = t; j < 2048; j += 256) hist2z[L*2048 + j] = 0u;
  } else {
    for (int j = t; j < LIST_CAP; j += 256) listsz[(size_t)L*LIST_CAP + j] = 0ull;
    if (t < NSUB) scntz[(L*NSUB + t)*16] = 0u;
  }
  for (int j = t; j < 2048; j += 256){
    unsigned int s = 0u;
    if (nrep == NREP){
#pragma unroll
      for (int r = 0; r < NREP; ++r) s += src[((r*4) + L)*2048 + j];
    } else {
      s = src[L*2048 + j];
    }
    lhist[j] = s;
  }
  __syncthreads();
  if (t < 64){
    int lane = t;
    unsigned int krem = (pass == 0) ? NMS_PRE : state[2*L + 1];
    unsigned int Pfx  = (pass == 0) ? 0u      : state[2*L];
    unsigned int carry = 0;
    for (int ch = 0; ch < 32; ++ch){
      unsigned int cnt = lhist[2047 - (ch*64 + lane)];
      unsigned int pfx = cnt;
#pragma unroll
      for (int off = 1; off < 64; off <<= 1){
        unsigned int u = __shfl_up(pfx, off);
        if (lane >= off) pfx += u;
      }
      unsigned int C = carry + pfx;
      ull bal = __ballot(C >= krem);
      if (bal){
        int fl2 = __ffsll(bal) - 1;
        unsigned int Cf = __shfl(C, fl2);
        unsigned int cf = __shfl(cnt, fl2);
        if (lane == 0){
          unsigned int b = (unsigned int)(2047 - (ch*64 + fl2));
          state[2*L]     = (pass == 0) ? (b << 21) : (Pfx | (b << 10));
          state[2*L + 1] = krem - (Cf - cf);
        }
        break;
      }
      carry = __shfl(C, 63);
    }
  }
}

// ---------------- stage 3: compact keys >= T (pair/thread) ------------------
__global__ void __launch_bounds__(512) compact_kernel(Ptrs P, const unsigned int* keys,
                        const unsigned int* state, unsigned int* scnt, ull* lists){
  int ip = blockIdx.x*512 + threadIdx.x;
  int f = ip << 1;
  if (f >= P.ntot) return;
  int L = level_of(f, P);
  uint2 kk = *(const uint2*)(keys + f);
  unsigned int T = state[2*L];
  unsigned int sub = (unsigned int)blockIdx.x & (NSUB - 1);
  if (kk.x >= T){
    unsigned int pos = atomicAdd(&scnt[(L*NSUB + sub)*16], 1u);
    if (pos < SUBCAP){
      unsigned int i = (unsigned int)(f - P.off[L]);
      lists[(size_t)L*LIST_CAP + sub*SUBCAP + pos] = ((ull)kk.x << 32) | (ull)(~i);
    }
  }
  if (kk.y >= T){
    unsigned int pos = atomicAdd(&scnt[(L*NSUB + sub)*16], 1u);
    if (pos < SUBCAP){
      unsigned int i = (unsigned int)(f + 1 - P.off[L]);
      lists[(size_t)L*LIST_CAP + sub*SUBCAP + pos] = ((ull)kk.y << 32) | (ull)(~i);
    }
  }
}

// ---------------- stage 4: hybrid bitonic sort -> sorted indices ------------
// Narrow kernel (4 blocks): sort ONLY — scattered gather stays in its own
// wide kernel (R8 lesson: fusing gather here throttles MLP to 4 CUs).
__global__ void __launch_bounds__(1024) sort_idx(const ull* lists, unsigned int* sidx){
  __shared__ ull buf[LIST_CAP];
  int L = blockIdx.x;
  int t = threadIdx.x;
  int e1 = t + 1024;
  const ull* src = lists + (size_t)L*LIST_CAP;
  ull v0 = src[t];
  ull v1 = src[e1];
  for (int k = 2; k <= 2048; k <<= 1){
    for (int j = k >> 1; j > 0; j >>= 1){
      bool hi0 = (((t  & j) == 0) == ((t  & k) == 0));
      bool hi1 = (((e1 & j) == 0) == ((e1 & k) == 0));
      if (j >= 1024){
        cxpair(v0, v1, hi0);           // partner is own second element
      } else if (j >= 64){
        __syncthreads();
        buf[t] = v0; buf[e1] = v1;
        __syncthreads();
        ull p0 = buf[t ^ j];
        ull p1 = buf[e1 ^ j];
        v0 = cx_keep(v0, p0, hi0);
        v1 = cx_keep(v1, p1, hi1);
      } else {
        ull p0 = __shfl_xor(v0, j);
        ull p1 = __shfl_xor(v1, j);
        v0 = cx_keep(v0, p0, hi0);
        v1 = cx_keep(v1, p1, hi1);
      }
    }
  }
  if (t < NMS_PRE) sidx[L*NMS_PRE + t] = ~((unsigned int)(v0 & 0xFFFFFFFFu));
}

// ---------------- stage 4b: gather + decode (wide grid for MLP) ------------
__global__ void __launch_bounds__(64) gather_decode(Ptrs P, const unsigned int* sidx,
                        float* boxes_pool, float* scores_pool){
  int r = blockIdx.x*64 + threadIdx.x;
  if (r >= POOL) return;
  int L = r / NMS_PRE;
  unsigned int i = sidx[r];
  const float* bp = P.bbox[L] + (size_t)i * 6;
  const float* pp = P.pts[L]  + (size_t)i * 3;
  float p0 = bp[0], p1 = bp[1], p2 = bp[2], p3 = bp[3], p4 = bp[4], p5 = bp[5];
  float cx = pp[0] + (p1 - p0) * 0.5f;
  float cy = pp[1] + (p3 - p2) * 0.5f;
  float cz = pp[2] + (p5 - p4) * 0.5f;
  float w = p0 + p1, l = p2 + p3, h = p4 + p5;
  float* bo = boxes_pool + (size_t)r * 6;
  bo[0] = cx; bo[1] = cy; bo[2] = cz; bo[3] = w; bo[4] = l; bo[5] = h;
  float cs = sigmoidf_(P.cent[L][i]);
  const float* cl = P.cls[L] + (size_t)i * N_CLASSES;
#pragma unroll
  for (int c = 0; c < N_CLASSES; ++c)
    scores_pool[(size_t)c * POOL + r] = sigmoidf_(cl[c]) * cs;
}

// ---------------- stage 5: fused per-class top-500 + NMS -------------------
// Unlike R4's class_nms, inputs are L2-hot coalesced pools (scores_pool,
// boxes_pool) — no scattered-HBM phase. aabb lives in LDS (aliased over dead
// keyS); maskG/flagsG/aabb globals and 2 dispatches deleted.
__global__ void __launch_bounds__(1024) class_topk_nms(const float* scores_pool,
                        const float* boxes_pool, float* out){
  __shared__ ull maskS[512*8];        // 32KB suppression bitmask
  __shared__ ull comp[512];           // survivors, then sorted winners
  __shared__ float boxA[8][512];      // mn0,mn1,mn2,mx0,mx1,mx2,vol,sval (16KB)
  __shared__ unsigned int histS[256];
  __shared__ unsigned int wsum[16], wpre[16];
  __shared__ ull vbitsS[8], flgS[8], remS[8];
  __shared__ unsigned int sP, sK, sCnt;
  unsigned int* keyS = (unsigned int*)&boxA[0][0];   // phase-A alias (16KB)
  int c = blockIdx.x;
  int t = threadIdx.x;
  int w = t >> 6, lane = t & 63;

  // ---- phase A: keys from coalesced score row
  for (int j = t; j < 4096; j += 1024){
    unsigned int k = 0u;
    if (j < POOL){
      float s = scores_pool[(size_t)c*POOL + j];
      float sval = (s > SCORE_THR) ? s : -1.0f;
      k = fsort(sval);
    }
    keyS[j] = k;
  }
  if (t == 0){ sP = 0u; sK = K_NMS; sCnt = 0u; }
  __syncthreads();

  // exact 500th-largest key via 4x8-bit radix select
  for (int pass = 0; pass < 4; ++pass){
    int shift = 24 - 8*pass;
    if (t < 256) histS[t] = 0u;
    __syncthreads();
    unsigned int Pfx = sP;
    for (int j = t; j < 4096; j += 1024){
      unsigned int k = keyS[j];
      if ((((ull)(k ^ Pfx)) >> (shift + 8)) == 0ull)
        atomicAdd(&histS[(k >> shift) & 0xFFu], 1u);
    }
    __syncthreads();
    if (w == 0){
      unsigned int krem = sK;
      unsigned int carry = 0;
      for (int ch = 0; ch < 4; ++ch){
        unsigned int cnt = histS[255 - (ch*64 + lane)];
        unsigned int pfx = cnt;
#pragma unroll
        for (int off = 1; off < 64; off <<= 1){
          unsigned int u = __shfl_up(pfx, off);
          if (lane >= off) pfx += u;
        }
        unsigned int C = carry + pfx;
        ull bal = __ballot(C >= krem);
        if (bal){
          int fl = __ffsll(bal) - 1;
          unsigned int Cf = __shfl(C, fl);
          unsigned int cf = __shfl(cnt, fl);
          if (lane == 0){
            sP = Pfx | ((unsigned int)(255 - (ch*64 + fl)) << shift);
            sK = krem - (Cf - cf);
          }
          break;
        }
        carry = __shfl(C, 63);
      }
    }
    __syncthreads();
  }
  unsigned int T = sP, need = sK;

  // ordered tie rank via block prefix scan; thread t owns keyS[4t..4t+4)
  unsigned int loc[4]; unsigned int ct = 0;
#pragma unroll
  for (int q = 0; q < 4; ++q){
    unsigned int k = keyS[4*t + q];
    loc[q] = k;
    ct += (k == T) ? 1u : 0u;
  }
  unsigned int inc = ct;
#pragma unroll
  for (int off = 1; off < 64; off <<= 1){
    unsigned int u = __shfl_up(inc, off);
    if (lane >= off) inc += u;
  }
  if (lane == 63) wsum[w] = inc;
  __syncthreads();
  if (t < 16){
    unsigned int v = wsum[t];
    unsigned int pincl = v;
#pragma unroll
    for (int off = 1; off < 16; off <<= 1){
      unsigned int u = __shfl_up(pincl, off);
      if (t >= off) pincl += u;
    }
    wpre[t] = pincl - v;
  }
  __syncthreads();
  unsigned int excl = wpre[w] + (inc - ct);

  // compact exactly 500 survivors: key>T, plus ==T ties in index order
#pragma unroll
  for (int q = 0; q < 4; ++q){
    unsigned int k = loc[q];
    bool surv = false;
    if (k > T) surv = true;
    else if (k == T){ surv = (excl < need); excl += 1u; }
    if (surv){
      unsigned int pos = atomicAdd(&sCnt, 1u);
      if (pos < 512)
        comp[pos] = ((ull)k << 32) | (ull)(~(unsigned int)(4*t + q));
    }
  }
  __syncthreads();   // keyS dead from here; boxA written after sort

  // hybrid bitonic desc over 512 elements (threads t<512 own elem t)
  ull v0 = 0ull;
  if (t < 512 && t < (int)sCnt) v0 = comp[t];
  for (int k = 2; k <= 512; k <<= 1){
    for (int j = k >> 1; j > 0; j >>= 1){
      if (j >= 64){
        __syncthreads();
        if (t < 512) comp[t] = v0;
        __syncthreads();
        if (t < 512){
          ull p0 = comp[t ^ j];
          bool hi0 = (((t & j) == 0) == ((t & k) == 0));
          v0 = cx_keep(v0, p0, hi0);
        }
      } else {
        if (t < 512){
          ull p0 = __shfl_xor(v0, j);
          bool hi0 = (((t & j) == 0) == ((t & k) == 0));
          v0 = cx_keep(v0, p0, hi0);
        }
      }
    }
  }
  __syncthreads();   // all comp/keyS traffic done before boxA overwrite

  // ---- phase B: decode winners -> out + boxA (AABB/vol/sval in LDS)
  if (t < 512){
    float mn0 = 0.f, mn1 = 0.f, mn2 = 0.f, mx0 = 0.f, mx1 = 0.f, mx2 = 0.f;
    float vol = 0.f, sval = -1.0f;
    if (t < K_NMS){
      unsigned int jj = ~((unsigned int)(v0 & 0xFFFFFFFFu));
      sval = fsort_inv((unsigned int)(v0 >> 32));
      int o = c*K_NMS + t;
      const float* bp = boxes_pool + (size_t)jj * 6;
      float b0 = bp[0], b1 = bp[1], b2 = bp[2], b3 = bp[3], b4 = bp[4], b5 = bp[5];
      float* ob = out + (size_t)o * 6;
      ob[0] = b0; ob[1] = b1; ob[2] = b2; ob[3] = b3; ob[4] = b4; ob[5] = b5;
      out[54000 + o] = sval;
      out[63000 + o] = (float)c;
      mn0 = b0 - b3*0.5f; mx0 = b0 + b3*0.5f;
      mn1 = b1 - b4*0.5f; mx1 = b1 + b4*0.5f;
      mn2 = b2 - b5*0.5f; mx2 = b2 + b5*0.5f;
      vol = fmaxf(mx0 - mn0, 0.f) * fmaxf(mx1 - mn1, 0.f) * fmaxf(mx2 - mn2, 0.f);
    }
    boxA[0][t] = mn0; boxA[1][t] = mn1; boxA[2][t] = mn2;
    boxA[3][t] = mx0; boxA[4][t] = mx1; boxA[5][t] = mx2;
    boxA[6][t] = vol; boxA[7][t] = sval;
  }
  __syncthreads();

  // ---- phase C: suppression mask build — 2 rows/iteration across 16 waves.
  {
    int col = t & 511;
    float cmn0 = boxA[0][col], cmn1 = boxA[1][col], cmn2 = boxA[2][col];
    float cmx0 = boxA[3][col], cmx1 = boxA[4][col], cmx2 = boxA[5][col];
    float cvol = boxA[6][col];
    bool colv = (col < K_NMS);
    int half = t >> 9;
    int w7 = w & 7;
    for (int i = 0; i < K_NMS; i += 2){
      int r = i + half;
      float rmn0 = boxA[0][r], rmn1 = boxA[1][r], rmn2 = boxA[2][r];
      float rmx0 = boxA[3][r], rmx1 = boxA[4][r], rmx2 = boxA[5][r];
      float rvol = boxA[6][r];
      float lt0 = fmaxf(rmn0, cmn0), lt1 = fmaxf(rmn1, cmn1), lt2 = fmaxf(rmn2, cmn2);
      float rb0 = fminf(rmx0, cmx0), rb1 = fminf(rmx1, cmx1), rb2 = fminf(rmx2, cmx2);
      float inter = fmaxf(rb0 - lt0, 0.f) * fmaxf(rb1 - lt1, 0.f) * fmaxf(rb2 - lt2, 0.f);
      float denom = rvol + cvol - inter + 1e-6f;
      bool s = colv && (col > r) && (inter / denom > IOU_THR);
      ull m = __ballot(s);
      if (lane == 0) maskS[r*8 + w7] = m;
    }
  }
  __syncthreads();

  // per-row nonzero flags + valid bits
  if (t < 512){
    bool nz = false;
    if (t < K_NMS){
      ull o8 = 0ull;
#pragma unroll
      for (int z = 0; z < 8; ++z) o8 |= maskS[t*8 + z];
      nz = (o8 != 0ull);
    }
    ull bal = __ballot(nz);
    if (lane == 0) flgS[w] = bal;
    ull vbb = __ballot(boxA[7][t] > SCORE_THR);
    if (lane == 0) vbitsS[w] = vbb;
  }
  __syncthreads();

  // ---- phase D: greedy — replicated bitset + event skipping (wave 0)
  if (w == 0){
    ull rem[8];
#pragma unroll
    for (int q = 0; q < 8; ++q) rem[q] = ~vbitsS[q];   // sup0 = !valid
#pragma unroll
    for (int q = 0; q < 8; ++q){
      ull cand = flgS[q] & ~rem[q];                    // alive rows that suppress
      while (cand){
        int b = __ffsll(cand) - 1;
        int i = q*64 + b;
#pragma unroll
        for (int z = 0; z < 8; ++z) rem[z] |= maskS[i*8 + z];
        ull above = (b < 63) ? (~0ull << (b + 1)) : 0ull;
        cand = flgS[q] & ~rem[q] & above;              // masks only set bits > i
      }
    }
    if (lane == 0){
#pragma unroll
      for (int q = 0; q < 8; ++q) remS[q] = rem[q];
    }
  }
  __syncthreads();
  if (t < K_NMS)
    out[72000 + c*K_NMS + t] = ((remS[t >> 6] >> (t & 63)) & 1ull) ? 0.0f : 1.0f;
}

// ---------------------------------------------------------------------------
extern "C" void kernel_launch(void* const* d_in, const int* in_sizes, int n_in,
                              void* d_out, int out_size, void* d_ws, size_t ws_size,
                              hipStream_t stream){
  Ptrs P;
  int off = 0;
  for (int L = 0; L < 4; ++L){
    P.cent[L] = (const float*)d_in[4*L + 0];
    P.bbox[L] = (const float*)d_in[4*L + 1];
    P.cls[L]  = (const float*)d_in[4*L + 2];
    P.pts[L]  = (const float*)d_in[4*L + 3];
    P.off[L]  = off;
    off += in_sizes[4*L + 0];
  }
  P.ntot = off;

  char* w = (char*)d_ws;
  size_t o = 0;
  auto alloc = [&](size_t bytes) -> char* {
    char* p = w + o;
    o = (o + bytes + 255) & ~(size_t)255;
    return p;
  };
  unsigned int* keys        = (unsigned int*)alloc((size_t)P.ntot * 4);
  unsigned int* hist_rep    = (unsigned int*)alloc((size_t)NREP * 4 * 2048 * 4);
  unsigned int* hist2       = (unsigned int*)alloc(4 * 2048 * 4);
  unsigned int* state       = (unsigned int*)alloc(4 * 2 * 4);
  unsigned int* scnt        = (unsigned int*)alloc(4 * NSUB * 16 * 4);
  ull* lists                = (ull*)alloc((size_t)4 * LIST_CAP * 8);
  unsigned int* sidx        = (unsigned int*)alloc((size_t)POOL * 4);
  float* boxes_pool         = (float*)alloc((size_t)POOL * 6 * 4);
  float* scores_pool        = (float*)alloc((size_t)N_CLASSES * POOL * 4);

  float* out = (float*)d_out;
  int npairs = P.ntot >> 1;                      // ntot is even (all level Ns even)
  int pgrid = (npairs + 511) / 512;

  init_kernel<<<64, 256, 0, stream>>>(hist_rep);
  compute_keys<<<pgrid, 512, 0, stream>>>(P, keys, hist_rep);
  scan_sel<<<4, 256, 0, stream>>>(hist_rep, NREP, state, 0, hist2, lists, scnt);
  hist_level<<<pgrid, 512, 0, stream>>>(P, keys, state, hist2);
  scan_sel<<<4, 256, 0, stream>>>(hist2, 1, state, 1, hist2, lists, scnt);
  compact_kernel<<<pgrid, 512, 0, stream>>>(P, keys, state, scnt, lists);
  sort_idx<<<4, 1024, 0, stream>>>(lists, sidx);
  gather_decode<<<(POOL + 63)/64, 64, 0, stream>>>(P, sidx, boxes_pool, scores_pool);
  class_topk_nms<<<N_CLASSES, 1024, 0, stream>>>(scores_pool, boxes_pool, out);
}

// Round 10
// 264.270 us; speedup vs baseline: 1.1561x; 1.1561x over previous
//
#include <hip/hip_runtime.h>
#include <math.h>

#define N_CLASSES 18
#define NMS_PRE   1000
#define K_NMS     500
#define POOL      4000      // 4 * NMS_PRE
#define LIST_CAP  2048
#define NREP      16        // replicated pass-0 histograms (atomic spread)
#define NSUB      16        // distributed compaction counters per level
#define SUBCAP    (LIST_CAP/NSUB)
#define IOU_THR   0.5f
#define SCORE_THR 0.01f

typedef unsigned long long ull;

struct Ptrs {
  const float* cent[4];
  const float* bbox[4];
  const float* cls[4];
  const float* pts[4];
  int off[4];
  int ntot;
};

__device__ __forceinline__ unsigned int fsort(float f){
  unsigned int b = __float_as_uint(f);
  return (b & 0x80000000u) ? ~b : (b | 0x80000000u);
}
__device__ __forceinline__ float fsort_inv(unsigned int k){
  unsigned int b = (k & 0x80000000u) ? (k & 0x7FFFFFFFu) : ~k;
  return __uint_as_float(b);
}
__device__ __forceinline__ float sigmoidf_(float x){
  return 1.0f / (1.0f + expf(-x));
}
__device__ __forceinline__ int level_of(int f, const Ptrs& P){
  return (f >= P.off[3]) ? 3 : (f >= P.off[2]) ? 2 : (f >= P.off[1]) ? 1 : 0;
}

// compare-exchange helpers for hybrid bitonic (desc).
__device__ __forceinline__ ull cx_keep(ull mine, ull part, bool keep_hi){
  ull mx = mine > part ? mine : part;
  ull mn = mine > part ? part : mine;
  return keep_hi ? mx : mn;
}
__device__ __forceinline__ void cxpair(ull &a, ull &b, bool a_hi){
  ull mx = a > b ? a : b;
  ull mn = a > b ? b : a;
  a = a_hi ? mx : mn;
  b = a_hi ? mn : mx;
}

// ---------------- stage 0: zero pass-0 histograms only ----------------------
// (hist2 zeroed by scan pass 0; lists/scnt by scan pass 1 — stream order.)
__global__ void __launch_bounds__(256) init_kernel(unsigned int* hist_rep){
  int tid = blockIdx.x*256 + threadIdx.x;
  int stride = gridDim.x*256;
  for (int j = tid; j < NREP*4*2048; j += stride) hist_rep[j] = 0u;
}

// ---------------- stage 1: fused max-score key + pass-0 histogram -----------
// One thread per POINT-PAIR: 2 rows = 144B = 9x float4, all 16B-aligned.
__global__ void __launch_bounds__(512) compute_keys(Ptrs P, unsigned int* keys,
                        unsigned int* hist_rep){
  __shared__ unsigned int lh[2048];
  int t = threadIdx.x;
  for (int j = t; j < 2048; j += 512) lh[j] = 0u;
  int ip = blockIdx.x*512 + t;          // pair index
  int f  = ip << 1;
  int rep = blockIdx.x & (NREP - 1);
  bool valid = f < P.ntot;              // ntot even -> full pair
  int f0 = blockIdx.x << 10;            // first point of block
  int fL = min(f0 + 1023, P.ntot - 1);
  bool uni = (level_of(f0, P) == level_of(fL, P)) && (f0 + 1023 < P.ntot);
  int Lb = level_of(f0, P);

  float mA = 0.f, mB = 0.f, cA = 0.f, cB = 0.f;
  int L = 0;
  if (valid){
    L = level_of(f, P);
    int i = f - P.off[L];
    const float4* q = (const float4*)(P.cls[L] + (size_t)i * N_CLASSES);
    float4 q0 = q[0], q1 = q[1], q2 = q[2], q3 = q[3], q4 = q[4];
    float4 q5 = q[5], q6 = q[6], q7 = q[7], q8 = q[8];
    mA = fmaxf(fmaxf(fmaxf(q0.x,q0.y), fmaxf(q0.z,q0.w)),
         fmaxf(fmaxf(fmaxf(q1.x,q1.y), fmaxf(q1.z,q1.w)),
         fmaxf(fmaxf(fmaxf(q2.x,q2.y), fmaxf(q2.z,q2.w)),
         fmaxf(fmaxf(fmaxf(q3.x,q3.y), fmaxf(q3.z,q3.w)),
               fmaxf(q4.x,q4.y)))));
    mB = fmaxf(fmaxf(q4.z,q4.w),
         fmaxf(fmaxf(fmaxf(q5.x,q5.y), fmaxf(q5.z,q5.w)),
         fmaxf(fmaxf(fmaxf(q6.x,q6.y), fmaxf(q6.z,q6.w)),
         fmaxf(fmaxf(fmaxf(q7.x,q7.y), fmaxf(q7.z,q7.w)),
               fmaxf(fmaxf(q8.x,q8.y), fmaxf(q8.z,q8.w))))));
    const float2 c2 = *(const float2*)(P.cent[L] + i);   // i even -> 8B aligned
    cA = c2.x; cB = c2.y;
  }
  __syncthreads();      // lh zero-init visible

  if (valid){
    // sigmoid monotone => sig(max)*sig(cent) == max_c(sig(c)*sig(cent))
    float sA = sigmoidf_(mA) * sigmoidf_(cA);
    float sB = sigmoidf_(mB) * sigmoidf_(cB);
    unsigned int kA = fsort(sA), kB = fsort(sB);
    *(uint2*)(keys + f) = make_uint2(kA, kB);            // coalesced 8B/lane
    if (uni){
      atomicAdd(&lh[kA >> 21], 1u);
      atomicAdd(&lh[kB >> 21], 1u);
    } else {
      unsigned int* hb = hist_rep + ((rep*4) + L)*2048;
      atomicAdd(&hb[kA >> 21], 1u);
      atomicAdd(&hb[kB >> 21], 1u);
    }
  }
  __syncthreads();
  if (uni){
    unsigned int* hb = hist_rep + ((rep*4) + Lb)*2048;
    for (int j = t; j < 2048; j += 512){
      unsigned int v = lh[j];
      if (v) atomicAdd(&hb[j], v);
    }
  }
}

// ---------------- stage 2: second 11-bit histogram pass (pair/thread) -------
__global__ void __launch_bounds__(512) hist_level(Ptrs P, const unsigned int* keys,
                        const unsigned int* state, unsigned int* hist2){
  int ip = blockIdx.x*512 + threadIdx.x;
  int f = ip << 1;
  if (f < P.ntot){
    int L = level_of(f, P);              // pair never straddles a level
    uint2 kk = *(const uint2*)(keys + f);
    unsigned int Pfx = state[2*L];
    unsigned int hi = Pfx >> 21;
    if ((kk.x >> 21) == hi) atomicAdd(&hist2[L*2048 + ((kk.x >> 10) & 0x7FFu)], 1u);
    if ((kk.y >> 21) == hi) atomicAdd(&hist2[L*2048 + ((kk.y >> 10) & 0x7FFu)], 1u);
  }
}

// ---------------- scan + select: one block per level ------------------------
// Piggy-backed zeroing: pass 0 zeroes hist2; pass 1 zeroes lists+scnt.
__global__ void __launch_bounds__(256) scan_sel(const unsigned int* src, int nrep,
                        unsigned int* state, int pass,
                        unsigned int* hist2z, ull* listsz, unsigned int* scntz){
  __shared__ unsigned int lhist[2048];
  int L = blockIdx.x, t = threadIdx.x;
  if (pass == 0){
    for (int j = t; j < 2048; j += 256) hist2z[L*2048 + j] = 0u;
  } else {
    for (int j = t; j < LIST_CAP; j += 256) listsz[(size_t)L*LIST_CAP + j] = 0ull;
    if (t < NSUB) scntz[(L*NSUB + t)*16] = 0u;
  }
  for (int j = t; j < 2048; j += 256){
    unsigned int s = 0u;
    if (nrep == NREP){
#pragma unroll
      for (int r = 0; r < NREP; ++r) s += src[((r*4) + L)*2048 + j];
    } else {
      s = src[L*2048 + j];
    }
    lhist[j] = s;
  }
  __syncthreads();
  if (t < 64){
    int lane = t;
    unsigned int krem = (pass == 0) ? NMS_PRE : state[2*L + 1];
    unsigned int Pfx  = (pass == 0) ? 0u      : state[2*L];
    unsigned int carry = 0;
    for (int ch = 0; ch < 32; ++ch){
      unsigned int cnt = lhist[2047 - (ch*64 + lane)];
      unsigned int pfx = cnt;
#pragma unroll
      for (int off = 1; off < 64; off <<= 1){
        unsigned int u = __shfl_up(pfx, off);
        if (lane >= off) pfx += u;
      }
      unsigned int C = carry + pfx;
      ull bal = __ballot(C >= krem);
      if (bal){
        int fl2 = __ffsll(bal) - 1;
        unsigned int Cf = __shfl(C, fl2);
        unsigned int cf = __shfl(cnt, fl2);
        if (lane == 0){
          unsigned int b = (unsigned int)(2047 - (ch*64 + fl2));
          state[2*L]     = (pass == 0) ? (b << 21) : (Pfx | (b << 10));
          state[2*L + 1] = krem - (Cf - cf);
        }
        break;
      }
      carry = __shfl(C, 63);
    }
  }
}

// ---------------- stage 3: compact keys >= T (pair/thread) ------------------
__global__ void __launch_bounds__(512) compact_kernel(Ptrs P, const unsigned int* keys,
                        const unsigned int* state, unsigned int* scnt, ull* lists){
  int ip = blockIdx.x*512 + threadIdx.x;
  int f = ip << 1;
  if (f >= P.ntot) return;
  int L = level_of(f, P);
  uint2 kk = *(const uint2*)(keys + f);
  unsigned int T = state[2*L];
  unsigned int sub = (unsigned int)blockIdx.x & (NSUB - 1);
  if (kk.x >= T){
    unsigned int pos = atomicAdd(&scnt[(L*NSUB + sub)*16], 1u);
    if (pos < SUBCAP){
      unsigned int i = (unsigned int)(f - P.off[L]);
      lists[(size_t)L*LIST_CAP + sub*SUBCAP + pos] = ((ull)kk.x << 32) | (ull)(~i);
    }
  }
  if (kk.y >= T){
    unsigned int pos = atomicAdd(&scnt[(L*NSUB + sub)*16], 1u);
    if (pos < SUBCAP){
      unsigned int i = (unsigned int)(f + 1 - P.off[L]);
      lists[(size_t)L*LIST_CAP + sub*SUBCAP + pos] = ((ull)kk.y << 32) | (ull)(~i);
    }
  }
}

// ---------------- stage 4: hybrid bitonic sort -> sorted indices ------------
// Narrow kernel (4 blocks): sort ONLY (R8 lesson: no fused gather here).
__global__ void __launch_bounds__(1024) sort_idx(const ull* lists, unsigned int* sidx){
  __shared__ ull buf[LIST_CAP];
  int L = blockIdx.x;
  int t = threadIdx.x;
  int e1 = t + 1024;
  const ull* src = lists + (size_t)L*LIST_CAP;
  ull v0 = src[t];
  ull v1 = src[e1];
  for (int k = 2; k <= 2048; k <<= 1){
    for (int j = k >> 1; j > 0; j >>= 1){
      bool hi0 = (((t  & j) == 0) == ((t  & k) == 0));
      bool hi1 = (((e1 & j) == 0) == ((e1 & k) == 0));
      if (j >= 1024){
        cxpair(v0, v1, hi0);           // partner is own second element
      } else if (j >= 64){
        __syncthreads();
        buf[t] = v0; buf[e1] = v1;
        __syncthreads();
        ull p0 = buf[t ^ j];
        ull p1 = buf[e1 ^ j];
        v0 = cx_keep(v0, p0, hi0);
        v1 = cx_keep(v1, p1, hi1);
      } else {
        ull p0 = __shfl_xor(v0, j);
        ull p1 = __shfl_xor(v1, j);
        v0 = cx_keep(v0, p0, hi0);
        v1 = cx_keep(v1, p1, hi1);
      }
    }
  }
  if (t < NMS_PRE) sidx[L*NMS_PRE + t] = ~((unsigned int)(v0 & 0xFFFFFFFFu));
}

// ---------------- stage 4b: gather + decode (wide grid for MLP) ------------
__global__ void __launch_bounds__(64) gather_decode(Ptrs P, const unsigned int* sidx,
                        float* boxes_pool, float* scores_pool){
  int r = blockIdx.x*64 + threadIdx.x;
  if (r >= POOL) return;
  int L = r / NMS_PRE;
  unsigned int i = sidx[r];
  const float* bp = P.bbox[L] + (size_t)i * 6;
  const float* pp = P.pts[L]  + (size_t)i * 3;
  float p0 = bp[0], p1 = bp[1], p2 = bp[2], p3 = bp[3], p4 = bp[4], p5 = bp[5];
  float cx = pp[0] + (p1 - p0) * 0.5f;
  float cy = pp[1] + (p3 - p2) * 0.5f;
  float cz = pp[2] + (p5 - p4) * 0.5f;
  float w = p0 + p1, l = p2 + p3, h = p4 + p5;
  float* bo = boxes_pool + (size_t)r * 6;
  bo[0] = cx; bo[1] = cy; bo[2] = cz; bo[3] = w; bo[4] = l; bo[5] = h;
  float cs = sigmoidf_(P.cent[L][i]);
  const float* cl = P.cls[L] + (size_t)i * N_CLASSES;
#pragma unroll
  for (int c = 0; c < N_CLASSES; ++c)
    scores_pool[(size_t)c * POOL + r] = sigmoidf_(cl[c]) * cs;
}

// ---------------- stage 5: per-class exact top-500 (radix select + sort512) -
__global__ void __launch_bounds__(1024) class_topk(const float* scores_pool, const float* boxes_pool,
                        float* out, float* aabb){
  __shared__ unsigned int keyS[4096];
  __shared__ ull comp[512];
  __shared__ unsigned int histS[256];
  __shared__ unsigned int wsum[16], wpre[16];
  __shared__ unsigned int sP, sK, sCnt;
  int c = blockIdx.x;
  int t = threadIdx.x;
  int w = t >> 6, lane = t & 63;

  for (int j = t; j < 4096; j += 1024){
    unsigned int k = 0u;
    if (j < POOL){
      float s = scores_pool[(size_t)c*POOL + j];
      float sval = (s > SCORE_THR) ? s : -1.0f;
      k = fsort(sval);
    }
    keyS[j] = k;
  }
  if (t == 0){ sP = 0u; sK = K_NMS; sCnt = 0u; }
  __syncthreads();

  // exact 500th-largest key via 4x8-bit radix select
  for (int pass = 0; pass < 4; ++pass){
    int shift = 24 - 8*pass;
    if (t < 256) histS[t] = 0u;
    __syncthreads();
    unsigned int Pfx = sP;
    for (int j = t; j < 4096; j += 1024){
      unsigned int k = keyS[j];
      if ((((ull)(k ^ Pfx)) >> (shift + 8)) == 0ull)
        atomicAdd(&histS[(k >> shift) & 0xFFu], 1u);
    }
    __syncthreads();
    if (w == 0){
      unsigned int krem = sK;
      unsigned int carry = 0;
      for (int ch = 0; ch < 4; ++ch){
        unsigned int cnt = histS[255 - (ch*64 + lane)];
        unsigned int pfx = cnt;
#pragma unroll
        for (int off = 1; off < 64; off <<= 1){
          unsigned int u = __shfl_up(pfx, off);
          if (lane >= off) pfx += u;
        }
        unsigned int C = carry + pfx;
        ull bal = __ballot(C >= krem);
        if (bal){
          int fl = __ffsll(bal) - 1;
          unsigned int Cf = __shfl(C, fl);
          unsigned int cf = __shfl(cnt, fl);
          if (lane == 0){
            sP = Pfx | ((unsigned int)(255 - (ch*64 + fl)) << shift);
            sK = krem - (Cf - cf);
          }
          break;
        }
        carry = __shfl(C, 63);
      }
    }
    __syncthreads();
  }
  unsigned int T = sP, need = sK;

  // ordered tie rank via block prefix scan; thread t owns keyS[4t..4t+4)
  unsigned int loc[4]; unsigned int ct = 0;
#pragma unroll
  for (int q = 0; q < 4; ++q){
    unsigned int k = keyS[4*t + q];
    loc[q] = k;
    ct += (k == T) ? 1u : 0u;
  }
  unsigned int inc = ct;
#pragma unroll
  for (int off = 1; off < 64; off <<= 1){
    unsigned int u = __shfl_up(inc, off);
    if (lane >= off) inc += u;
  }
  if (lane == 63) wsum[w] = inc;
  __syncthreads();
  if (t < 16){
    unsigned int v = wsum[t];
    unsigned int pincl = v;
#pragma unroll
    for (int off = 1; off < 16; off <<= 1){
      unsigned int u = __shfl_up(pincl, off);
      if (t >= off) pincl += u;
    }
    wpre[t] = pincl - v;
  }
  __syncthreads();
  unsigned int excl = wpre[w] + (inc - ct);

  // compact exactly 500 survivors: key>T, plus ==T ties in index order
#pragma unroll
  for (int q = 0; q < 4; ++q){
    unsigned int k = loc[q];
    bool surv = false;
    if (k > T) surv = true;
    else if (k == T){ surv = (excl < need); excl += 1u; }
    if (surv){
      unsigned int pos = atomicAdd(&sCnt, 1u);
      if (pos < 512)
        comp[pos] = ((ull)k << 32) | (ull)(~(unsigned int)(4*t + q));
    }
  }
  __syncthreads();

  // hybrid bitonic desc over 512 elements (threads t<512 own elem t)
  ull v0 = 0ull;
  if (t < 512 && t < (int)sCnt) v0 = comp[t];
  for (int k = 2; k <= 512; k <<= 1){
    for (int j = k >> 1; j > 0; j >>= 1){
      if (j >= 64){
        __syncthreads();
        if (t < 512) comp[t] = v0;
        __syncthreads();
        if (t < 512){
          ull p0 = comp[t ^ j];
          bool hi0 = (((t & j) == 0) == ((t & k) == 0));
          v0 = cx_keep(v0, p0, hi0);
        }
      } else {
        if (t < 512){
          ull p0 = __shfl_xor(v0, j);
          bool hi0 = (((t & j) == 0) == ((t & k) == 0));
          v0 = cx_keep(v0, p0, hi0);
        }
      }
    }
  }

  if (t < K_NMS){
    ull cm = v0;
    unsigned int j = ~((unsigned int)(cm & 0xFFFFFFFFu));
    float sval = fsort_inv((unsigned int)(cm >> 32));
    int o = c*K_NMS + t;
    const float* bp = boxes_pool + (size_t)j * 6;
    float b0 = bp[0], b1 = bp[1], b2 = bp[2], b3 = bp[3], b4 = bp[4], b5 = bp[5];
    float* ob = out + (size_t)o * 6;
    ob[0] = b0; ob[1] = b1; ob[2] = b2; ob[3] = b3; ob[4] = b4; ob[5] = b5;
    out[54000 + o] = sval;
    out[63000 + o] = (float)c;
    float mn0 = b0 - b3*0.5f, mx0 = b0 + b3*0.5f;
    float mn1 = b1 - b4*0.5f, mx1 = b1 + b4*0.5f;
    float mn2 = b2 - b5*0.5f, mx2 = b2 + b5*0.5f;
    float vol = fmaxf(mx0 - mn0, 0.f) * fmaxf(mx1 - mn1, 0.f) * fmaxf(mx2 - mn2, 0.f);
    float* ap = aabb + ((size_t)c*512 + t) * 8;
    ap[0] = mn0; ap[1] = mn1; ap[2] = mn2; ap[3] = mx0; ap[4] = mx1; ap[5] = mx2;
    ap[6] = vol; ap[7] = sval;
  }
}

// ---------------- stage 6a: NMS mask build + per-row nonzero flags ----------
__global__ void __launch_bounds__(512) nms_mask(const float* aabb, ull* maskG, ull* flagsG){
  __shared__ float smn0[512], smn1[512], smn2[512];
  __shared__ float smx0[512], smx1[512], smx2[512];
  __shared__ float svol[512];
  __shared__ ull rowbuf[64*8];
  int c = blockIdx.y, chunk = blockIdx.x;
  int t = threadIdx.x, w = t >> 6, lane = t & 63;
  float mn0 = 0.f, mn1 = 0.f, mn2 = 0.f, mx0 = 0.f, mx1 = 0.f, mx2 = 0.f, vol = 0.f;
  if (t < K_NMS){
    const float* ap = aabb + ((size_t)c*512 + t) * 8;
    mn0 = ap[0]; mn1 = ap[1]; mn2 = ap[2];
    mx0 = ap[3]; mx1 = ap[4]; mx2 = ap[5]; vol = ap[6];
  }
  smn0[t] = mn0; smn1[t] = mn1; smn2[t] = mn2;
  smx0[t] = mx0; smx1[t] = mx1; smx2[t] = mx2;
  svol[t] = vol;
  __syncthreads();
  int i0 = chunk * 64, i1 = min(i0 + 64, K_NMS);
  for (int i = i0; i < i1; ++i){
    float lt0 = fmaxf(smn0[i], mn0), lt1 = fmaxf(smn1[i], mn1), lt2 = fmaxf(smn2[i], mn2);
    float rb0 = fminf(smx0[i], mx0), rb1 = fminf(smx1[i], mx1), rb2 = fminf(smx2[i], mx2);
    float inter = fmaxf(rb0 - lt0, 0.f) * fmaxf(rb1 - lt1, 0.f) * fmaxf(rb2 - lt2, 0.f);
    float denom = svol[i] + vol - inter + 1e-6f;
    bool s = (t < K_NMS) && (t > i) && (inter / denom > IOU_THR);
    ull m = __ballot(s);
    if (lane == 0){
      maskG[((size_t)c*K_NMS + i)*8 + w] = m;
      rowbuf[(i - i0)*8 + w] = m;
    }
  }
  __syncthreads();
  if (t < 64){
    int r = i0 + t;
    bool nz = false;
    if (r < K_NMS){
      ull o = 0ull;
#pragma unroll
      for (int z = 0; z < 8; ++z) o |= rowbuf[t*8 + z];
      nz = (o != 0ull);
    }
    ull bal = __ballot(nz);
    if (t == 0) flagsG[(size_t)c*8 + chunk] = bal;
  }
}

// ---------------- stage 6b: greedy — replicated bitset + event skipping -----
__global__ void __launch_bounds__(512) nms_greedy(const float* aabb, const ull* maskG,
                        const ull* flagsG, float* keep_out){
  __shared__ ull maskS[K_NMS*8];
  __shared__ ull vbitsS[8], remS[8];
  int c = blockIdx.x, t = threadIdx.x, w = t >> 6, lane = t & 63;
  ull flg[8];
#pragma unroll
  for (int q = 0; q < 8; ++q) flg[q] = flagsG[(size_t)c*8 + q];
  for (int j = t; j < K_NMS*8; j += 512) maskS[j] = maskG[(size_t)c*K_NMS*8 + j];
  float sv = (t < K_NMS) ? aabb[((size_t)c*512 + t)*8 + 7] : -1.0f;
  ull vb = __ballot(sv > SCORE_THR);
  if (lane == 0) vbitsS[w] = vb;
  __syncthreads();
  if (w == 0){
    ull rem[8];
#pragma unroll
    for (int q = 0; q < 8; ++q) rem[q] = ~vbitsS[q];   // sup0 = !valid
#pragma unroll
    for (int q = 0; q < 8; ++q){
      ull cand = flg[q] & ~rem[q];                     // alive rows that suppress
      while (cand){
        int b = __ffsll(cand) - 1;
        int i = q*64 + b;
#pragma unroll
        for (int z = 0; z < 8; ++z) rem[z] |= maskS[i*8 + z];
        ull above = (b < 63) ? (~0ull << (b + 1)) : 0ull;
        cand = flg[q] & ~rem[q] & above;               // masks only set bits > i
      }
    }
    if (lane == 0){
#pragma unroll
      for (int q = 0; q < 8; ++q) remS[q] = rem[q];
    }
  }
  __syncthreads();
  if (t < K_NMS)
    keep_out[c*K_NMS + t] = ((remS[t >> 6] >> (t & 63)) & 1ull) ? 0.0f : 1.0f;
}

// ---------------------------------------------------------------------------
extern "C" void kernel_launch(void* const* d_in, const int* in_sizes, int n_in,
                              void* d_out, int out_size, void* d_ws, size_t ws_size,
                              hipStream_t stream){
  Ptrs P;
  int off = 0;
  for (int L = 0; L < 4; ++L){
    P.cent[L] = (const float*)d_in[4*L + 0];
    P.bbox[L] = (const float*)d_in[4*L + 1];
    P.cls[L]  = (const float*)d_in[4*L + 2];
    P.pts[L]  = (const float*)d_in[4*L + 3];
    P.off[L]  = off;
    off += in_sizes[4*L + 0];
  }
  P.ntot = off;

  char* w = (char*)d_ws;
  size_t o = 0;
  auto alloc = [&](size_t bytes) -> char* {
    char* p = w + o;
    o = (o + bytes + 255) & ~(size_t)255;
    return p;
  };
  unsigned int* keys        = (unsigned int*)alloc((size_t)P.ntot * 4);
  unsigned int* hist_rep    = (unsigned int*)alloc((size_t)NREP * 4 * 2048 * 4);
  unsigned int* hist2       = (unsigned int*)alloc(4 * 2048 * 4);
  unsigned int* state       = (unsigned int*)alloc(4 * 2 * 4);
  unsigned int* scnt        = (unsigned int*)alloc(4 * NSUB * 16 * 4);
  ull* lists                = (ull*)alloc((size_t)4 * LIST_CAP * 8);
  unsigned int* sidx        = (unsigned int*)alloc((size_t)POOL * 4);
  float* boxes_pool         = (float*)alloc((size_t)POOL * 6 * 4);
  float* scores_pool        = (float*)alloc((size_t)N_CLASSES * POOL * 4);
  float* aabb               = (float*)alloc((size_t)N_CLASSES * 512 * 8 * 4);
  ull* maskG                = (ull*)alloc((size_t)N_CLASSES * K_NMS * 8 * 8);
  ull* flagsG               = (ull*)alloc((size_t)N_CLASSES * 8 * 8);

  float* out = (float*)d_out;
  int npairs = P.ntot >> 1;                      // ntot is even (all level Ns even)
  int pgrid = (npairs + 511) / 512;

  init_kernel<<<64, 256, 0, stream>>>(hist_rep);
  compute_keys<<<pgrid, 512, 0, stream>>>(P, keys, hist_rep);
  scan_sel<<<4, 256, 0, stream>>>(hist_rep, NREP, state, 0, hist2, lists, scnt);
  hist_level<<<pgrid, 512, 0, stream>>>(P, keys, state, hist2);
  scan_sel<<<4, 256, 0, stream>>>(hist2, 1, state, 1, hist2, lists, scnt);
  compact_kernel<<<pgrid, 512, 0, stream>>>(P, keys, state, scnt, lists);
  sort_idx<<<4, 1024, 0, stream>>>(lists, sidx);
  gather_decode<<<(POOL + 63)/64, 64, 0, stream>>>(P, sidx, boxes_pool, scores_pool);
  class_topk<<<N_CLASSES, 1024, 0, stream>>>(scores_pool, boxes_pool, out, aabb);
  nms_mask<<<dim3(8, N_CLASSES), 512, 0, stream>>>(aabb, maskG, flagsG);
  nms_greedy<<<N_CLASSES, 512, 0, stream>>>(aabb, maskG, flagsG, out + 72000);
}